// Round 1
// baseline (724.116 us; speedup 1.0000x reference)
//
#include <hip/hip_runtime.h>

#define NT 16384
#define DM 4096
#define NE 64
#define TOPK 8
#define NWAVES 8          // waves per workgroup (K-split factor)
#define KCH (DM / NWAVES) // 512 K-elements per wave
#define WIN 16            // k-window per inner step
#define NWIN (KCH / WIN)  // 32 windows

__global__ __launch_bounds__(512, 2) void gate_kernel(
    const float* __restrict__ x,
    const float* __restrict__ W,
    int* __restrict__ out) {

  const int lane = threadIdx.x & 63;
  // force wave-uniform so W accesses become scalar (s_load) loads
  const int wid  = __builtin_amdgcn_readfirstlane((int)(threadIdx.x >> 6));
  const int tok  = blockIdx.x * 64 + lane;
  const int kbase = wid * KCH;

  float acc[NE];
#pragma unroll
  for (int e = 0; e < NE; ++e) acc[e] = 0.f;

  const float* xrow = x + (size_t)tok * DM + kbase;

  // double-buffered per-lane x window (16 floats = 4 x float4)
  float4 xa[4], xb[4];
#pragma unroll
  for (int v = 0; v < 4; ++v) xa[v] = ((const float4*)xrow)[v];

  for (int w = 0; w < NWIN; ++w) {
    if (w + 1 < NWIN) {
      const float* xn = xrow + (w + 1) * WIN;
#pragma unroll
      for (int v = 0; v < 4; ++v) xb[v] = ((const float4*)xn)[v];
    }
    const int k0 = kbase + w * WIN;
#pragma unroll 4
    for (int e = 0; e < NE; ++e) {
      const float4* wv = (const float4*)(W + e * DM + k0); // wave-uniform
      float s = 0.f;
#pragma unroll
      for (int v = 0; v < 4; ++v) {
        float4 wf = wv[v];
        s = fmaf(xa[v].x, wf.x, s);
        s = fmaf(xa[v].y, wf.y, s);
        s = fmaf(xa[v].z, wf.z, s);
        s = fmaf(xa[v].w, wf.w, s);
      }
      acc[e] += s; // two-level accumulation for accuracy
    }
#pragma unroll
    for (int v = 0; v < 4; ++v) xa[v] = xb[v];
  }

  // ---- cross-wave K reduction: pairwise tree via LDS (2 slots) ----
  __shared__ float red[2][64][68]; // 68-float stride: 16B-aligned rows, 34816 B

  auto dump = [&](int slot) {
#pragma unroll
    for (int v = 0; v < 16; ++v)
      *(float4*)&red[slot][lane][v * 4] = *(const float4*)&acc[v * 4];
  };
  auto addin = [&](int slot) {
#pragma unroll
    for (int v = 0; v < 16; ++v) {
      float4 t = *(const float4*)&red[slot][lane][v * 4];
      acc[v * 4 + 0] += t.x;
      acc[v * 4 + 1] += t.y;
      acc[v * 4 + 2] += t.z;
      acc[v * 4 + 3] += t.w;
    }
  };

  // step 1: waves 4,5 -> slots 0,1 ; waves 0,1 absorb
  if (wid == 4) dump(0);
  if (wid == 5) dump(1);
  __syncthreads();
  if (wid == 0) addin(0);
  if (wid == 1) addin(1);
  __syncthreads();
  // step 2: waves 6,7 -> slots 0,1 ; waves 2,3 absorb
  if (wid == 6) dump(0);
  if (wid == 7) dump(1);
  __syncthreads();
  if (wid == 2) addin(0);
  if (wid == 3) addin(1);
  __syncthreads();
  // step 3: waves 2,3 -> slots 0,1 ; waves 0,1 absorb
  if (wid == 2) dump(0);
  if (wid == 3) dump(1);
  __syncthreads();
  if (wid == 0) addin(0);
  if (wid == 1) addin(1);
  __syncthreads();
  // step 4: wave 1 -> slot 0 ; wave 0 absorbs
  if (wid == 1) dump(0);
  __syncthreads();

  if (wid == 0) {
    addin(0);

    // ---- top-8 by repeated argmax (stable: lowest index wins ties) ----
    int idx[TOPK];
#pragma unroll
    for (int p = 0; p < TOPK; ++p) {
      float m = -3.402823466e38f;
      int mi = 0;
#pragma unroll
      for (int e = 0; e < NE; ++e) {
        bool b = acc[e] > m; // strict >, ascending scan => first occurrence
        m  = b ? acc[e] : m;
        mi = b ? e : mi;
      }
      idx[p] = mi;
#pragma unroll
      for (int e = 0; e < NE; ++e)
        acc[e] = (e == mi) ? -3.402823466e38f : acc[e];
    }

    int4* op = (int4*)(out + (size_t)tok * TOPK);
    op[0] = make_int4(idx[0], idx[1], idx[2], idx[3]);
    op[1] = make_int4(idx[4], idx[5], idx[6], idx[7]);
  }
}

extern "C" void kernel_launch(void* const* d_in, const int* in_sizes, int n_in,
                              void* d_out, int out_size, void* d_ws, size_t ws_size,
                              hipStream_t stream) {
  const float* x = (const float*)d_in[0];
  const float* W = (const float*)d_in[1];
  int* out = (int*)d_out;
  (void)in_sizes; (void)n_in; (void)out_size; (void)d_ws; (void)ws_size;

  dim3 grid(NT / 64);   // 256 workgroups, one per 64 tokens
  dim3 block(512);      // 8 waves: K-split
  hipLaunchKernelGGL(gate_kernel, grid, block, 0, stream, x, W, out);
}

// Round 2
// 366.611 us; speedup vs baseline: 1.9752x; 1.9752x over previous
//
#include <hip/hip_runtime.h>

#define NT 16384
#define DM 4096
#define NE 64
#define TOPK 8
#define NWAVES 8          // waves per workgroup (K-split factor)
#define KCH (DM / NWAVES) // 512 K-elements per wave
#define WIN 16            // k-window per inner step
#define NWIN (KCH / WIN)  // 32 windows

__global__ __launch_bounds__(512, 2) void gate_kernel(
    const float* __restrict__ x,
    const float* __restrict__ W,
    int* __restrict__ out) {

  const int lane = threadIdx.x & 63;
  const int wid  = __builtin_amdgcn_readfirstlane((int)(threadIdx.x >> 6));
  const int tok  = blockIdx.x * 64 + lane;
  const int kbase = wid * KCH;

  float acc[NE];
#pragma unroll
  for (int e = 0; e < NE; ++e) acc[e] = 0.f;

  const float* xrow = x + (size_t)tok * DM + kbase;

  // double-buffered per-lane x window (16 floats = 4 x float4)
  float4 xa[4], xb[4];
#pragma unroll
  for (int v = 0; v < 4; ++v) xa[v] = ((const float4*)xrow)[v];

  for (int w = 0; w < NWIN; ++w) {
    if (w + 1 < NWIN) {
      const float* xn = xrow + (w + 1) * WIN;
#pragma unroll
      for (int v = 0; v < 4; ++v) xb[v] = ((const float4*)xn)[v];
    }
    const int k0 = kbase + w * WIN;
    // FULL unroll: every acc[e] index must be compile-time constant,
    // otherwise the array is demoted to scratch (R1: VGPR=44, 724us).
#pragma unroll
    for (int e = 0; e < NE; ++e) {
      const float4* wv = (const float4*)(W + e * DM + k0); // wave-uniform
      float s = 0.f;
#pragma unroll
      for (int v = 0; v < 4; ++v) {
        float4 wf = wv[v];
        s = fmaf(xa[v].x, wf.x, s);
        s = fmaf(xa[v].y, wf.y, s);
        s = fmaf(xa[v].z, wf.z, s);
        s = fmaf(xa[v].w, wf.w, s);
      }
      acc[e] += s; // two-level accumulation for accuracy
    }
#pragma unroll
    for (int v = 0; v < 4; ++v) xa[v] = xb[v];
  }

  // ---- cross-wave K reduction: pairwise tree via LDS (2 slots) ----
  __shared__ float red[2][64][68]; // 68-float stride: 16B-aligned rows, 34816 B

  auto dump = [&](int slot) {
#pragma unroll
    for (int v = 0; v < 16; ++v)
      *(float4*)&red[slot][lane][v * 4] = *(const float4*)&acc[v * 4];
  };
  auto addin = [&](int slot) {
#pragma unroll
    for (int v = 0; v < 16; ++v) {
      float4 t = *(const float4*)&red[slot][lane][v * 4];
      acc[v * 4 + 0] += t.x;
      acc[v * 4 + 1] += t.y;
      acc[v * 4 + 2] += t.z;
      acc[v * 4 + 3] += t.w;
    }
  };

  // step 1: waves 4,5 -> slots 0,1 ; waves 0,1 absorb
  if (wid == 4) dump(0);
  if (wid == 5) dump(1);
  __syncthreads();
  if (wid == 0) addin(0);
  if (wid == 1) addin(1);
  __syncthreads();
  // step 2: waves 6,7 -> slots 0,1 ; waves 2,3 absorb
  if (wid == 6) dump(0);
  if (wid == 7) dump(1);
  __syncthreads();
  if (wid == 2) addin(0);
  if (wid == 3) addin(1);
  __syncthreads();
  // step 3: waves 2,3 -> slots 0,1 ; waves 0,1 absorb
  if (wid == 2) dump(0);
  if (wid == 3) dump(1);
  __syncthreads();
  if (wid == 0) addin(0);
  if (wid == 1) addin(1);
  __syncthreads();
  // step 4: wave 1 -> slot 0 ; wave 0 absorbs
  if (wid == 1) dump(0);
  __syncthreads();

  if (wid == 0) {
    addin(0);

    // ---- top-8 by repeated argmax (stable: lowest index wins ties) ----
    int idx[TOPK];
#pragma unroll
    for (int p = 0; p < TOPK; ++p) {
      float m = -3.402823466e38f;
      int mi = 0;
#pragma unroll
      for (int e = 0; e < NE; ++e) {
        bool b = acc[e] > m; // strict >, ascending scan => first occurrence
        m  = b ? acc[e] : m;
        mi = b ? e : mi;
      }
      idx[p] = mi;
#pragma unroll
      for (int e = 0; e < NE; ++e)
        acc[e] = (e == mi) ? -3.402823466e38f : acc[e];
    }

    int4* op = (int4*)(out + (size_t)tok * TOPK);
    op[0] = make_int4(idx[0], idx[1], idx[2], idx[3]);
    op[1] = make_int4(idx[4], idx[5], idx[6], idx[7]);
  }
}

extern "C" void kernel_launch(void* const* d_in, const int* in_sizes, int n_in,
                              void* d_out, int out_size, void* d_ws, size_t ws_size,
                              hipStream_t stream) {
  const float* x = (const float*)d_in[0];
  const float* W = (const float*)d_in[1];
  int* out = (int*)d_out;
  (void)in_sizes; (void)n_in; (void)out_size; (void)d_ws; (void)ws_size;

  dim3 grid(NT / 64);   // 256 workgroups, one per 64 tokens
  dim3 block(512);      // 8 waves: K-split
  hipLaunchKernelGGL(gate_kernel, grid, block, 0, stream, x, W, out);
}